// Round 17
// baseline (596.344 us; speedup 1.0000x reference)
//
#include <hip/hip_runtime.h>

#define NB 4
#define NT 8192
#define NC 64
#define NS 256
#define NV 256
#define NL 30

typedef __attribute__((ext_vector_type(8))) short bf16x8;
typedef __attribute__((ext_vector_type(4))) float f32x4;
typedef unsigned short ushort_t;

#define MFMA(a, b, c) __builtin_amdgcn_mfma_f32_16x16x32_bf16(a, b, c, 0, 0, 0)

// weight arena (bf16 elems)
#define OFF_WCAT 0
#define SZ_WCAT  (NL * 16384)            // swizzled [l][kk=4][n=128][j=32]
#define OFF_RW   (OFF_WCAT + SZ_WCAT)
#define SZ_RW    (NL * 4096)             // swizzled [l][kk=2][n=64][j=32]
#define OFF_SWG  (OFF_RW + SZ_RW)
#define SZ_SWG   (6 * 81920)             // per group g: [kk=10][n=256][j=32]
#define OFF_W0   (OFF_SWG + SZ_SWG)      // [kk=8][n=256][j=32]
#define OFF_W1   (OFF_W0 + 65536)        // [kk=8][n=256][j=32]
#define TOTAL_W  (OFF_W1 + 65536)        // 1,236,992 elems (2.42 MB)
#define N_PREP   (TOTAL_W + 1536)        // + sbsum_g[6][256] fp32

#define X_ELEMS  (NB * NT * NC)          // 2,097,152 (4 MB bf16)
#define SK_ELEMS (NB * NT * NS)          // 8,388,608 (16 MB bf16)
#define G_ELEMS  (NB * NT * NC)          // gate slot (4 MB bf16)
#define WS_NEEDED ((size_t)(2 * X_ELEMS + SK_ELEMS + 5 * G_ELEMS + TOTAL_W) * 2 \
                   + 1536 * 4)           // 46.4 MB

__device__ inline ushort_t f2bu(float f) {
  union { float f; unsigned u; } v; v.f = f;
  unsigned r = v.u + 0x7FFFu + ((v.u >> 16) & 1u);
  return (ushort_t)(r >> 16);
}
__device__ inline float b2f(ushort_t h) {
  union { unsigned u; float f; } v; v.u = ((unsigned)h) << 16; return v.f;
}

__global__ void sentinel_kernel(float* __restrict__ out) {
  if (threadIdx.x == 0) out[0] = -1234.0f;
}
__global__ void zero_kernel(float* __restrict__ out) {
  if (threadIdx.x == 0) out[0] = 0.0f;
}

// ---------------------------------------------------------------------------
__global__ __launch_bounds__(256) void prep_kernel(
    const float* __restrict__ cw, const float* __restrict__ rw,
    const float* __restrict__ sw, const float* __restrict__ w0,
    const float* __restrict__ w1, const float* __restrict__ sb_all,
    ushort_t* __restrict__ wt, float* __restrict__ sbg)
{
  int idx = blockIdx.x * 256 + threadIdx.x;
  if (idx >= N_PREP) return;
  if (idx >= TOTAL_W) {
    int j = idx - TOTAL_W;
    int g = j >> 8, n = j & 255;
    float s = 0.f;
#pragma unroll
    for (int jj = 0; jj < 5; ++jj) s += sb_all[(5 * g + jj) * 256 + n];
    sbg[j] = s;
    return;
  }
  float v;
  if (idx < OFF_RW) {
    int e = idx; int l = e >> 14; int r = e & 16383;
    int kk = r >> 12, n = (r >> 5) & 127, j = r & 31;
    int k = kk * 32 + j, tap = k >> 6, c = k & 63;
    v = cw[(((l * 2 + tap) << 6) + c) * 128 + n];
  } else if (idx < OFF_SWG) {
    int e = idx - OFF_RW; int l = e >> 12; int r = e & 4095;
    int kk = r >> 11, n = (r >> 5) & 63, j = r & 31;
    int k = kk * 32 + j;
    v = rw[((l << 6) + k) * 64 + n];
  } else if (idx < OFF_W0) {
    int e = idx - OFF_SWG; int g = e / 81920; int r = e % 81920;
    int kk = r >> 13; int rem = r & 8191;
    int n = rem >> 5, jj = rem & 31;
    int k = kk * 32 + jj;                       // 0..319
    v = sw[(size_t)(320 * g + k) * 256 + n];
  } else if (idx < OFF_W1) {
    int e = idx - OFF_W0;
    int kk = e >> 13; int rem = e & 8191;
    int n = rem >> 5, jj = rem & 31;
    int k = kk * 32 + jj;
    v = w0[k * 256 + n];
  } else {
    int e = idx - OFF_W1;
    int kk = e >> 13; int rem = e & 8191;
    int n = rem >> 5, jj = rem & 31;
    int k = kk * 32 + jj;
    v = w1[k * 256 + n];
  }
  wt[idx] = f2bu(v);
}

// ---------------------------------------------------------------------------
// chain5 v5: 5 fused layers (d=1,2,4,8,16) + own-group skip accumulation in
// registers (waves 2-5) with direct skip RMW; NO gate writes. For l0==0 the
// embedding is computed in-kernel during staging (embed dispatch deleted).
// 512 blocks x 384 threads (6 waves); block owns 64 rows + 32 halo.
// ---------------------------------------------------------------------------
__global__ __launch_bounds__(384) void chain5_kernel(
    const ushort_t* __restrict__ xin, ushort_t* __restrict__ xout,
    ushort_t* __restrict__ skip,
    const int* __restrict__ wf, const float* __restrict__ embed,
    const ushort_t* __restrict__ wt,
    const float* __restrict__ cb_all, const float* __restrict__ rb_all,
    const ushort_t* __restrict__ swg_own, const float* __restrict__ sbg_own,
    int l0, int first)
{
  __shared__ __align__(16) ushort_t xt[96][72];   // 13.5 KB
  __shared__ __align__(16) ushort_t gt[96][72];   // 13.5 KB

  const int tid = threadIdx.x;
  const int w = tid >> 6, lane = tid & 63;      // w = tile 0..5
  const int quad = lane >> 4, c16 = lane & 15;
  const int bb = blockIdx.x >> 7;               // 128 blocks per batch
  const int t0 = (blockIdx.x & 127) << 6;       // 64 own rows
  const size_t row0 = (size_t)bb * NT;

  // ---- stage x rows t0-32 .. t0+63 (embed fused for first group) ----
#pragma unroll
  for (int i = 0; i < 2; ++i) {
    int e = tid + i * 384;
    int r = e >> 3, c0 = (e & 7) * 8;
    int t = t0 - 32 + r;
    bf16x8 v;
    if (t >= 0) {
      if (l0 == 0) {
        int id = (t == 0) ? 128 : wf[row0 + t - 1];
        const float* ep = embed + id * 64 + c0;
        float4 lo = *(const float4*)ep;
        float4 hi = *(const float4*)(ep + 4);
        v[0] = (short)f2bu(lo.x); v[1] = (short)f2bu(lo.y);
        v[2] = (short)f2bu(lo.z); v[3] = (short)f2bu(lo.w);
        v[4] = (short)f2bu(hi.x); v[5] = (short)f2bu(hi.y);
        v[6] = (short)f2bu(hi.z); v[7] = (short)f2bu(hi.w);
      } else {
        v = *(const bf16x8*)(xin + (row0 + t) * 64 + c0);
      }
    } else {
      bf16x8 z = {0, 0, 0, 0, 0, 0, 0, 0};
      v = z;
    }
    *(bf16x8*)&xt[r][c0] = v;
  }
  __syncthreads();

  // ---- own-group skip accumulator (waves 2-5 = real rows t0..t0+63) ----
  f32x4 sacc[16];
#pragma unroll
  for (int nt = 0; nt < 16; ++nt) { f32x4 z = {0.f, 0.f, 0.f, 0.f}; sacc[nt] = z; }

  for (int j = 0; j < 5; ++j) {
    const int l = l0 + j;
    const int d = 1 << j;
    const ushort_t* wcat = wt + OFF_WCAT + l * 16384;
    const ushort_t* rww  = wt + OFF_RW + l * 4096;
    const float* cb = cb_all + l * 128;
    const float* rb = rb_all + l * 64;

    // ---- phase A: A-frags from xt (cross-tile halo reads) ----
    bf16x8 af[4];
    {
      int lr = w * 16 + c16;
#pragma unroll
      for (int kk = 0; kk < 4; ++kk) {
        int rr = (kk < 2) ? lr - d : lr;
        int ch = (kk & 1) * 32 + quad * 8;
        if (rr >= 0) af[kk] = *(const bf16x8*)&xt[rr][ch];
        else { bf16x8 z = {0, 0, 0, 0, 0, 0, 0, 0}; af[kk] = z; }
      }
    }
    __syncthreads();   // all A reads done before any xt update

    // ---- phase B: GEMM1 -> gate; GEMM2 -> xt +=; skip GEMM -> sacc ----
    {
      f32x4 acc[8];
#pragma unroll
      for (int q = 0; q < 4; ++q) {
        float ba = cb[q * 16 + c16], bs = cb[q * 16 + c16 + 64];
        f32x4 va = {ba, ba, ba, ba}, vb = {bs, bs, bs, bs};
        acc[q] = va; acc[4 + q] = vb;
      }
#pragma unroll
      for (int kk = 0; kk < 4; ++kk) {
        const ushort_t* wp = wcat + kk * 4096 + c16 * 32 + quad * 8;
#pragma unroll
        for (int q = 0; q < 4; ++q) {
          acc[q]     = MFMA(af[kk], *(const bf16x8*)(wp + q * 512), acc[q]);
          acc[4 + q] = MFMA(af[kk], *(const bf16x8*)(wp + q * 512 + 2048), acc[4 + q]);
        }
      }
#pragma unroll
      for (int q = 0; q < 4; ++q)
#pragma unroll
        for (int r = 0; r < 4; ++r) {
          float e2 = __expf(2.f * acc[q][r]);
          float th = (e2 - 1.f) / (e2 + 1.f);
          float sg = 1.f / (1.f + __expf(-acc[4 + q][r]));
          gt[w * 16 + quad * 4 + r][q * 16 + c16] = f2bu(th * sg);
        }

      bf16x8 gf0 = *(const bf16x8*)&gt[w * 16 + c16][quad * 8];
      bf16x8 gf1 = *(const bf16x8*)&gt[w * 16 + c16][32 + quad * 8];

      f32x4 acc2[4];
#pragma unroll
      for (int q = 0; q < 4; ++q) {
        float bv = rb[q * 16 + c16];
        f32x4 z = {bv, bv, bv, bv};
        acc2[q] = z;
      }
      const ushort_t* wp2 = rww + c16 * 32 + quad * 8;
#pragma unroll
      for (int q = 0; q < 4; ++q)
        acc2[q] = MFMA(gf0, *(const bf16x8*)(wp2 + q * 512), acc2[q]);
#pragma unroll
      for (int q = 0; q < 4; ++q)
        acc2[q] = MFMA(gf1, *(const bf16x8*)(wp2 + q * 512 + 2048), acc2[q]);
#pragma unroll
      for (int q = 0; q < 4; ++q) {
        int n = q * 16 + c16;
#pragma unroll
        for (int r = 0; r < 4; ++r) {
          int rowi = w * 16 + quad * 4 + r;
          xt[rowi][n] = f2bu(b2f(xt[rowi][n]) + acc2[q][r]);
        }
      }

      // own-group skip accumulation (real rows only: waves 2-5)
      if (w >= 2) {
        const ushort_t* wps = swg_own + (2 * j) * 8192 + c16 * 32 + quad * 8;
#pragma unroll
        for (int nt = 0; nt < 16; ++nt)
          sacc[nt] = MFMA(gf0, *(const bf16x8*)(wps + nt * 512), sacc[nt]);
        const ushort_t* wps2 = wps + 8192;
#pragma unroll
        for (int nt = 0; nt < 16; ++nt)
          sacc[nt] = MFMA(gf1, *(const bf16x8*)(wps2 + nt * 512), sacc[nt]);
      }
    }
    __syncthreads();   // xt complete for next layer's phase A
  }

  // ---- write back x rows 32..95 ----
  {
    int e = tid;
    {
      int r = e >> 3, c0 = (e & 7) * 8;
      *(bf16x8*)(xout + (row0 + t0 + r) * 64 + c0) = *(const bf16x8*)&xt[32 + r][c0];
    }
    e = tid + 384;
    if (e < 512) {
      int r = e >> 3, c0 = (e & 7) * 8;
      *(bf16x8*)(xout + (row0 + t0 + r) * 64 + c0) = *(const bf16x8*)&xt[32 + r][c0];
    }
  }

  // ---- skip write/RMW (waves 2-5, own rows) ----
  if (w >= 2) {
    const int rbase = t0 + (w - 2) * 16 + quad * 4;
#pragma unroll
    for (int nt = 0; nt < 16; ++nt) {
      int n = nt * 16 + c16;
      float sbn = sbg_own[n];
#pragma unroll
      for (int r = 0; r < 4; ++r) {
        size_t idx = (row0 + rbase + r) * 256 + n;
        float old = first ? 0.f : b2f(skip[idx]);
        skip[idx] = f2bu(old + sacc[nt][r] + sbn);
      }
    }
  }
}

// ---------------------------------------------------------------------------
// Single layer (d >= 32): unchanged from R16. 512 blocks x 256 threads.
// ---------------------------------------------------------------------------
__global__ __launch_bounds__(256, 4) void layer_kernel(
    const ushort_t* __restrict__ xin, ushort_t* __restrict__ xout,
    ushort_t* __restrict__ gate_out,
    const ushort_t* __restrict__ wcat_s, const float* __restrict__ cb,
    const ushort_t* __restrict__ rww,    const float* __restrict__ rb,
    int d, int write_res)
{
  __shared__ __align__(16) ushort_t lwc[16384];    // 32 KB conv weights
  __shared__ __align__(16) ushort_t gt[64][72];    // 9 KB gate tile

  const int tid = threadIdx.x;
  const int w = tid >> 6, lane = tid & 63;
  const int quad = lane >> 4, c16 = lane & 15;
  const int bb = blockIdx.x >> 7;
  const int t0 = (blockIdx.x & 127) << 6;
  const int tb = t0 + w * 16;
  const size_t row0 = (size_t)bb * NT;

  {
    bf16x8* dst = (bf16x8*)lwc;
    const bf16x8* s1 = (const bf16x8*)wcat_s;
#pragma unroll
    for (int i = 0; i < 8; ++i) dst[tid + i * 256] = s1[tid + i * 256];
  }

  const int tA = tb + c16;
  bf16x8 af[4];
#pragma unroll
  for (int kk = 0; kk < 4; ++kk) {
    int ts = (kk < 2) ? (tA - d) : tA;
    int ch = (kk & 1) * 32 + quad * 8;
    if (ts >= 0) {
      af[kk] = *(const bf16x8*)(xin + (row0 + ts) * 64 + ch);
    } else {
      bf16x8 z = {0, 0, 0, 0, 0, 0, 0, 0};
      af[kk] = z;
    }
  }
  __syncthreads();

#pragma unroll
  for (int q = 0; q < 4; ++q) {
    int na = q * 16 + c16;
    int nb2 = na + 64;
    float ba = cb[na], bs = cb[nb2];
    f32x4 va = {ba, ba, ba, ba}, vb = {bs, bs, bs, bs};
#pragma unroll
    for (int kk = 0; kk < 4; ++kk) {
      va = MFMA(af[kk], *(const bf16x8*)&lwc[kk * 4096 + na * 32 + quad * 8], va);
      vb = MFMA(af[kk], *(const bf16x8*)&lwc[kk * 4096 + nb2 * 32 + quad * 8], vb);
    }
#pragma unroll
    for (int r = 0; r < 4; ++r) {
      float e2 = __expf(2.f * va[r]);
      float th = (e2 - 1.f) / (e2 + 1.f);
      float sg = 1.f / (1.f + __expf(-vb[r]));
      gt[w * 16 + quad * 4 + r][q * 16 + c16] = f2bu(th * sg);
    }
  }

  // wave-local gate write FIRST (no barrier; store latency overlaps GEMM2)
#pragma unroll
  for (int i = 0; i < 2; ++i) {
    int e = lane + i * 64;
    int rr = w * 16 + (e >> 3), c0 = (e & 7) * 8;
    *(bf16x8*)(gate_out + (row0 + t0 + rr) * 64 + c0) = *(const bf16x8*)&gt[rr][c0];
  }

  if (write_res) {
    bf16x8 gf0 = *(const bf16x8*)&gt[w * 16 + c16][quad * 8];
    bf16x8 gf1 = *(const bf16x8*)&gt[w * 16 + c16][32 + quad * 8];

    ushort_t xold[4][4];
#pragma unroll
    for (int q = 0; q < 4; ++q) {
      int n = q * 16 + c16;
#pragma unroll
      for (int r = 0; r < 4; ++r)
        xold[q][r] = xin[(row0 + tb + quad * 4 + r) * 64 + n];
    }

    const ushort_t* wp2 = rww + c16 * 32 + quad * 8;
#pragma unroll
    for (int q = 0; q < 4; ++q) {
      int n = q * 16 + c16;
      float bv = rb[n];
      f32x4 acc = {bv, bv, bv, bv};
      acc = MFMA(gf0, *(const bf16x8*)(wp2 + q * 512), acc);
      acc = MFMA(gf1, *(const bf16x8*)(wp2 + q * 512 + 2048), acc);
#pragma unroll
      for (int r = 0; r < 4; ++r) {
        size_t idx = (row0 + tb + quad * 4 + r) * 64 + n;
        xout[idx] = f2bu(b2f(xold[q][r]) + acc[r]);
      }
    }
  }
}

// ---------------------------------------------------------------------------
// Skip-group GEMM with LDS-staged weight chunks (3 uses: singles groups).
// ---------------------------------------------------------------------------
__global__ __launch_bounds__(256) void skip_kernel(
    ushort_t* __restrict__ skip, const ushort_t* __restrict__ gates,
    const ushort_t* __restrict__ swg, const float* __restrict__ sbg)
{
  __shared__ __align__(16) ushort_t wbuf[8192];   // 16 KB chunk
  const int tid = threadIdx.x;
  const int w = tid >> 6, lane = tid & 63;
  const int quad = lane >> 4, c16 = lane & 15;
  const int bb = blockIdx.x >> 7;
  const int t0 = (blockIdx.x & 127) << 6;
  const int tb = t0 + w * 16;
  const size_t row0 = (size_t)bb * NT;

  f32x4 acc[16];
#pragma unroll
  for (int nt = 0; nt < 16; ++nt) { f32x4 z = {0.f, 0.f, 0.f, 0.f}; acc[nt] = z; }

  const size_t arow = (row0 + tb + c16) * 64;
  for (int kk = 0; kk < 10; ++kk) {
#pragma unroll
    for (int i = 0; i < 4; ++i)
      ((bf16x8*)wbuf)[tid + i * 256] = ((const bf16x8*)(swg + kk * 8192))[tid + i * 256];
    __syncthreads();

    int slot = kk >> 1;
    bf16x8 af = *(const bf16x8*)(gates + (size_t)slot * G_ELEMS + arow +
                                 (kk & 1) * 32 + quad * 8);
    const ushort_t* wp = wbuf + c16 * 32 + quad * 8;
#pragma unroll
    for (int nt = 0; nt < 16; ++nt)
      acc[nt] = MFMA(af, *(const bf16x8*)(wp + nt * 512), acc[nt]);
    __syncthreads();
  }

#pragma unroll
  for (int nt = 0; nt < 16; ++nt) {
    int n = nt * 16 + c16;
    float sbn = sbg[n];
#pragma unroll
    for (int r = 0; r < 4; ++r) {
      size_t idx = (row0 + tb + quad * 4 + r) * 256 + n;
      skip[idx] = f2bu(b2f(skip[idx]) + acc[nt][r] + sbn);
    }
  }
}

// ---------------------------------------------------------------------------
// Head with LDS-staged weight chunks (unchanged from R16).
// ---------------------------------------------------------------------------
__global__ __launch_bounds__(256) void head_kernel(
    const ushort_t* __restrict__ skip,
    const ushort_t* __restrict__ w0T, const float* __restrict__ b0,
    const ushort_t* __restrict__ w1T, const float* __restrict__ b1,
    const int* __restrict__ wf, const int* __restrict__ lens,
    float* __restrict__ loss)
{
  __shared__ __align__(16) ushort_t wbuf[8192];
  __shared__ __align__(16) ushort_t tile[64][264];
  const int tid = threadIdx.x;
  const int w = tid >> 6, lane = tid & 63;
  const int quad = lane >> 4, c16 = lane & 15;
  const int bb = blockIdx.x >> 7;
  const int t0 = (blockIdx.x & 127) << 6;
  const int tb = t0 + w * 16;
  const size_t row0 = (size_t)bb * NT;
  const int mylen = lens[bb];

  f32x4 acc[16];
#pragma unroll
  for (int nt = 0; nt < 16; ++nt) {
    float bv = b0[nt * 16 + c16];
    f32x4 z = {bv, bv, bv, bv};
    acc[nt] = z;
  }
  const ushort_t* sp = skip + (row0 + tb + c16) * 256 + quad * 8;
  for (int kk = 0; kk < 8; ++kk) {
#pragma unroll
    for (int i = 0; i < 4; ++i)
      ((bf16x8*)wbuf)[tid + i * 256] = ((const bf16x8*)(w0T + kk * 8192))[tid + i * 256];
    __syncthreads();
    bf16x8 af = *(const bf16x8*)(sp + kk * 32);
    const ushort_t* wp = wbuf + c16 * 32 + quad * 8;
#pragma unroll
    for (int nt = 0; nt < 16; ++nt)
      acc[nt] = MFMA(af, *(const bf16x8*)(wp + nt * 512), acc[nt]);
    __syncthreads();
  }
#pragma unroll
  for (int nt = 0; nt < 16; ++nt)
#pragma unroll
    for (int r = 0; r < 4; ++r)
      tile[w * 16 + quad * 4 + r][nt * 16 + c16] = f2bu(fmaxf(acc[nt][r], 0.f));

  f32x4 acc2[16];
#pragma unroll
  for (int nt = 0; nt < 16; ++nt) {
    float bv = b1[nt * 16 + c16];
    f32x4 z = {bv, bv, bv, bv};
    acc2[nt] = z;
  }
  for (int kk = 0; kk < 8; ++kk) {
#pragma unroll
    for (int i = 0; i < 4; ++i)
      ((bf16x8*)wbuf)[tid + i * 256] = ((const bf16x8*)(w1T + kk * 8192))[tid + i * 256];
    __syncthreads();
    bf16x8 hf = *(const bf16x8*)&tile[w * 16 + c16][kk * 32 + quad * 8];
    const ushort_t* wp = wbuf + c16 * 32 + quad * 8;
#pragma unroll
    for (int nt = 0; nt < 16; ++nt)
      acc2[nt] = MFMA(hf, *(const bf16x8*)(wp + nt * 512), acc2[nt]);
    __syncthreads();
  }

  int lblv[4];
#pragma unroll
  for (int r = 0; r < 4; ++r)
    lblv[r] = wf[row0 + tb + quad * 4 + r];

  float local = 0.f;
#pragma unroll
  for (int r = 0; r < 4; ++r) {
    float m = -1e30f, tv = -1e30f;
#pragma unroll
    for (int nt = 0; nt < 16; ++nt) {
      float v = acc2[nt][r];
      m = fmaxf(m, v);
      if (lblv[r] == nt * 16 + c16) tv = v;
    }
#pragma unroll
    for (int dd = 1; dd < 16; dd <<= 1) m = fmaxf(m, __shfl_xor(m, dd));
    float s = 0.f;
#pragma unroll
    for (int nt = 0; nt < 16; ++nt) s += __expf(acc2[nt][r] - m);
#pragma unroll
    for (int dd = 1; dd < 16; dd <<= 1) {
      s += __shfl_xor(s, dd);
      tv = fmaxf(tv, __shfl_xor(tv, dd));
    }
    int t = tb + quad * 4 + r;
    if (c16 == 0 && t < mylen) local += (m + __logf(s)) - tv;
  }
#pragma unroll
  for (int dd = 1; dd < 64; dd <<= 1) local += __shfl_xor(local, dd);
  if (lane == 0 && local != 0.f) atomicAdd(loss, local);
}

__global__ void finalize_kernel(const int* __restrict__ lens,
                                float* __restrict__ out)
{
  if (threadIdx.x == 0) {
    float den = 0.f;
    for (int b = 0; b < NB; ++b) {
      int l = lens[b];
      if (l > NT) l = NT;
      den += (float)l;
    }
    out[0] = out[0] / fmaxf(den, 1.f);
  }
}

// ---------------------------------------------------------------------------
extern "C" void kernel_launch(void* const* d_in, const int* in_sizes, int n_in,
                              void* d_out, int out_size, void* d_ws, size_t ws_size,
                              hipStream_t stream) {
  const int*   wf     = (const int*)d_in[0];
  const int*   lens   = (const int*)d_in[1];
  const float* embed  = (const float*)d_in[2];
  const float* conv_w = (const float*)d_in[3];
  const float* conv_b = (const float*)d_in[4];
  const float* res_w  = (const float*)d_in[5];
  const float* res_b  = (const float*)d_in[6];
  const float* skip_w = (const float*)d_in[7];
  const float* skip_b = (const float*)d_in[8];
  const float* w0     = (const float*)d_in[9];
  const float* b0     = (const float*)d_in[10];
  const float* w1     = (const float*)d_in[11];
  const float* b1     = (const float*)d_in[12];

  float* out = (float*)d_out;
  if (ws_size < WS_NEEDED) {
    sentinel_kernel<<<1, 64, 0, stream>>>(out);
    return;
  }

  ushort_t* x0    = (ushort_t*)d_ws;            // 4 MB
  ushort_t* x1    = x0 + X_ELEMS;               // 4 MB
  ushort_t* skip  = x1 + X_ELEMS;               // 16 MB
  ushort_t* gates = skip + SK_ELEMS;            // 5 x 4 MB
  ushort_t* wt    = gates + 5 * (size_t)G_ELEMS;// 2.42 MB
  float*    sbg   = (float*)(wt + TOTAL_W);     // 6 KB

  prep_kernel<<<(N_PREP + 255) / 256, 256, 0, stream>>>(
      conv_w, res_w, skip_w, w0, w1, skip_b, wt, sbg);
  zero_kernel<<<1, 64, 0, stream>>>(out);

  const ushort_t* xin = x0;
  ushort_t* xout = x1;
  static const int dil[NL] = {1, 2, 4, 8, 16, 32, 64, 128, 256, 512,
                              1, 2, 4, 8, 16, 32, 64, 128, 256, 512,
                              1, 2, 4, 8, 16, 32, 64, 128, 256, 512};
  for (int blk = 0; blk < 3; ++blk) {
    const int l0 = blk * 10;
    const int gown = 2 * blk;
    // fused: 5 layers + own-group skip (+ embed for blk==0)
    chain5_kernel<<<512, 384, 0, stream>>>(
        xin, xout, skip, wf, embed, wt, conv_b, res_b,
        wt + OFF_SWG + gown * 81920, sbg + gown * 256,
        l0, blk == 0 ? 1 : 0);
    { const ushort_t* t = xout; xout = (ushort_t*)xin; xin = t; }
    for (int l = l0 + 5; l < l0 + 10; ++l) {
      layer_kernel<<<512, 256, 0, stream>>>(
          xin, xout, gates + (size_t)(l % 5) * G_ELEMS,
          wt + OFF_WCAT + l * 16384, conv_b + l * 128,
          wt + OFF_RW + l * 4096,    res_b + l * 64,
          dil[l], l < NL - 1 ? 1 : 0);
      { const ushort_t* t = xout; xout = (ushort_t*)xin; xin = t; }
    }
    skip_kernel<<<512, 256, 0, stream>>>(
        skip, gates, wt + OFF_SWG + (2 * blk + 1) * 81920,
        sbg + (2 * blk + 1) * 256);
  }

  head_kernel<<<512, 256, 0, stream>>>(skip, wt + OFF_W0, b0, wt + OFF_W1, b1,
                                       wf, lens, out);
  finalize_kernel<<<1, 64, 0, stream>>>(lens, out);
}

// Round 18
// 529.182 us; speedup vs baseline: 1.1269x; 1.1269x over previous
//
#include <hip/hip_runtime.h>

#define NB 4
#define NT 8192
#define NC 64
#define NS 256
#define NV 256
#define NL 30

typedef __attribute__((ext_vector_type(8))) short bf16x8;
typedef __attribute__((ext_vector_type(4))) float f32x4;
typedef unsigned short ushort_t;

#define MFMA(a, b, c) __builtin_amdgcn_mfma_f32_16x16x32_bf16(a, b, c, 0, 0, 0)

// weight arena (bf16 elems)
#define OFF_WCAT 0
#define SZ_WCAT  (NL * 16384)            // swizzled [l][kk=4][n=128][j=32]
#define OFF_RW   (OFF_WCAT + SZ_WCAT)
#define SZ_RW    (NL * 4096)             // swizzled [l][kk=2][n=64][j=32]
#define OFF_SWG  (OFF_RW + SZ_RW)
#define SZ_SWG   (6 * 81920)             // per group g: [kk=10][n=256][j=32]
#define OFF_W0   (OFF_SWG + SZ_SWG)      // [kk=8][n=256][j=32]
#define OFF_W1   (OFF_W0 + 65536)        // [kk=8][n=256][j=32]
#define TOTAL_W  (OFF_W1 + 65536)        // 1,236,992 elems (2.42 MB)
#define N_PREP   (TOTAL_W + 1536)        // + sbsum_g[6][256] fp32

#define X_ELEMS  (NB * NT * NC)          // 2,097,152 (4 MB bf16)
#define SK_ELEMS (NB * NT * NS)          // 8,388,608 (16 MB bf16)
#define G_ELEMS  (NB * NT * NC)          // gate slot (4 MB bf16)
#define WS_NEEDED ((size_t)(2 * X_ELEMS + SK_ELEMS + 5 * G_ELEMS + TOTAL_W) * 2 \
                   + 1536 * 4)           // 46.4 MB

__device__ inline ushort_t f2bu(float f) {
  union { float f; unsigned u; } v; v.f = f;
  unsigned r = v.u + 0x7FFFu + ((v.u >> 16) & 1u);
  return (ushort_t)(r >> 16);
}
__device__ inline float b2f(ushort_t h) {
  union { unsigned u; float f; } v; v.u = ((unsigned)h) << 16; return v.f;
}

__global__ void sentinel_kernel(float* __restrict__ out) {
  if (threadIdx.x == 0) out[0] = -1234.0f;
}
__global__ void zero_kernel(float* __restrict__ out) {
  if (threadIdx.x == 0) out[0] = 0.0f;
}

// ---------------------------------------------------------------------------
__global__ __launch_bounds__(256) void prep_kernel(
    const float* __restrict__ cw, const float* __restrict__ rw,
    const float* __restrict__ sw, const float* __restrict__ w0,
    const float* __restrict__ w1, const float* __restrict__ sb_all,
    ushort_t* __restrict__ wt, float* __restrict__ sbg)
{
  int idx = blockIdx.x * 256 + threadIdx.x;
  if (idx >= N_PREP) return;
  if (idx >= TOTAL_W) {
    int j = idx - TOTAL_W;
    int g = j >> 8, n = j & 255;
    float s = 0.f;
#pragma unroll
    for (int jj = 0; jj < 5; ++jj) s += sb_all[(5 * g + jj) * 256 + n];
    sbg[j] = s;
    return;
  }
  float v;
  if (idx < OFF_RW) {
    int e = idx; int l = e >> 14; int r = e & 16383;
    int kk = r >> 12, n = (r >> 5) & 127, j = r & 31;
    int k = kk * 32 + j, tap = k >> 6, c = k & 63;
    v = cw[(((l * 2 + tap) << 6) + c) * 128 + n];
  } else if (idx < OFF_SWG) {
    int e = idx - OFF_RW; int l = e >> 12; int r = e & 4095;
    int kk = r >> 11, n = (r >> 5) & 63, j = r & 31;
    int k = kk * 32 + j;
    v = rw[((l << 6) + k) * 64 + n];
  } else if (idx < OFF_W0) {
    int e = idx - OFF_SWG; int g = e / 81920; int r = e % 81920;
    int kk = r >> 13; int rem = r & 8191;
    int n = rem >> 5, jj = rem & 31;
    int k = kk * 32 + jj;                       // 0..319
    v = sw[(size_t)(320 * g + k) * 256 + n];
  } else if (idx < OFF_W1) {
    int e = idx - OFF_W0;
    int kk = e >> 13; int rem = e & 8191;
    int n = rem >> 5, jj = rem & 31;
    int k = kk * 32 + jj;
    v = w0[k * 256 + n];
  } else {
    int e = idx - OFF_W1;
    int kk = e >> 13; int rem = e & 8191;
    int n = rem >> 5, jj = rem & 31;
    int k = kk * 32 + jj;
    v = w1[k * 256 + n];
  }
  wt[idx] = f2bu(v);
}

// ---------------------------------------------------------------------------
__global__ __launch_bounds__(256) void embed_kernel(
    const int* __restrict__ wf, const float* __restrict__ embed,
    ushort_t* __restrict__ x0)
{
  const int bidx = blockIdx.x;
  const int bb = bidx >> 7;
  const int t0 = (bidx & 127) << 6;
  const int pos0 = bb * NT + t0;
  for (int e = threadIdx.x; e < 64 * 64; e += 256) {
    int p = e >> 6, c = e & 63;
    int t = t0 + p;
    int id = (t == 0) ? 128 : wf[bb * NT + t - 1];
    x0[(size_t)(pos0 + p) * NC + c] = f2bu(embed[id * NC + c]);
  }
}

// ---------------------------------------------------------------------------
// chain5 (R13-proven): 5 fused layers (d=1,2,4,8,16). 512 blocks x 384
// threads (6 waves); block owns 64 rows + 32 halo = 96 LDS rows; 1 tile/wave;
// 2 blocks/CU. Halo validity: 1+2+4+8+16 = 31 <= 32. Writes gates slots 0-4.
// ---------------------------------------------------------------------------
__global__ __launch_bounds__(384) void chain5_kernel(
    const ushort_t* __restrict__ xin, ushort_t* __restrict__ xout,
    ushort_t* __restrict__ gates,
    const ushort_t* __restrict__ wt,
    const float* __restrict__ cb_all, const float* __restrict__ rb_all,
    int l0)
{
  __shared__ __align__(16) ushort_t xt[96][72];   // 13.5 KB
  __shared__ __align__(16) ushort_t gt[96][72];   // 13.5 KB

  const int tid = threadIdx.x;
  const int w = tid >> 6, lane = tid & 63;      // w = tile 0..5
  const int quad = lane >> 4, c16 = lane & 15;
  const int bb = blockIdx.x >> 7;               // 128 blocks per batch
  const int t0 = (blockIdx.x & 127) << 6;       // 64 own rows
  const size_t row0 = (size_t)bb * NT;

  // ---- stage x rows t0-32 .. t0+63 ----
#pragma unroll
  for (int i = 0; i < 2; ++i) {
    int e = tid + i * 384;
    int r = e >> 3, c0 = (e & 7) * 8;
    int t = t0 - 32 + r;
    bf16x8 v;
    if (t >= 0) v = *(const bf16x8*)(xin + (row0 + t) * 64 + c0);
    else { bf16x8 z = {0, 0, 0, 0, 0, 0, 0, 0}; v = z; }
    *(bf16x8*)&xt[r][c0] = v;
  }
  __syncthreads();

  for (int j = 0; j < 5; ++j) {
    const int l = l0 + j;
    const int d = 1 << j;
    const ushort_t* wcat = wt + OFF_WCAT + l * 16384;
    const ushort_t* rww  = wt + OFF_RW + l * 4096;
    const float* cb = cb_all + l * 128;
    const float* rb = rb_all + l * 64;

    // ---- phase A: A-frags from xt (cross-tile halo reads) ----
    bf16x8 af[4];
    {
      int lr = w * 16 + c16;
#pragma unroll
      for (int kk = 0; kk < 4; ++kk) {
        int rr = (kk < 2) ? lr - d : lr;
        int ch = (kk & 1) * 32 + quad * 8;
        if (rr >= 0) af[kk] = *(const bf16x8*)&xt[rr][ch];
        else { bf16x8 z = {0, 0, 0, 0, 0, 0, 0, 0}; af[kk] = z; }
      }
    }
    __syncthreads();   // all A reads done before any xt update

    // ---- phase B: GEMM1 -> gate -> gt; GEMM2 -> xt += ----
    {
      f32x4 acc[8];
#pragma unroll
      for (int q = 0; q < 4; ++q) {
        float ba = cb[q * 16 + c16], bs = cb[q * 16 + c16 + 64];
        f32x4 va = {ba, ba, ba, ba}, vb = {bs, bs, bs, bs};
        acc[q] = va; acc[4 + q] = vb;
      }
#pragma unroll
      for (int kk = 0; kk < 4; ++kk) {
        const ushort_t* wp = wcat + kk * 4096 + c16 * 32 + quad * 8;
#pragma unroll
        for (int q = 0; q < 4; ++q) {
          acc[q]     = MFMA(af[kk], *(const bf16x8*)(wp + q * 512), acc[q]);
          acc[4 + q] = MFMA(af[kk], *(const bf16x8*)(wp + q * 512 + 2048), acc[4 + q]);
        }
      }
#pragma unroll
      for (int q = 0; q < 4; ++q)
#pragma unroll
        for (int r = 0; r < 4; ++r) {
          float e2 = __expf(2.f * acc[q][r]);
          float th = (e2 - 1.f) / (e2 + 1.f);
          float sg = 1.f / (1.f + __expf(-acc[4 + q][r]));
          gt[w * 16 + quad * 4 + r][q * 16 + c16] = f2bu(th * sg);
        }

      bf16x8 gf0 = *(const bf16x8*)&gt[w * 16 + c16][quad * 8];
      bf16x8 gf1 = *(const bf16x8*)&gt[w * 16 + c16][32 + quad * 8];

      f32x4 acc2[4];
#pragma unroll
      for (int q = 0; q < 4; ++q) {
        float bv = rb[q * 16 + c16];
        f32x4 z = {bv, bv, bv, bv};
        acc2[q] = z;
      }
      const ushort_t* wp2 = rww + c16 * 32 + quad * 8;
#pragma unroll
      for (int q = 0; q < 4; ++q)
        acc2[q] = MFMA(gf0, *(const bf16x8*)(wp2 + q * 512), acc2[q]);
#pragma unroll
      for (int q = 0; q < 4; ++q)
        acc2[q] = MFMA(gf1, *(const bf16x8*)(wp2 + q * 512 + 2048), acc2[q]);
#pragma unroll
      for (int q = 0; q < 4; ++q) {
        int n = q * 16 + c16;
#pragma unroll
        for (int r = 0; r < 4; ++r) {
          int rowi = w * 16 + quad * 4 + r;
          xt[rowi][n] = f2bu(b2f(xt[rowi][n]) + acc2[q][r]);
        }
      }
    }
    __syncthreads();   // gt complete for coop write; xt complete for next j

    // ---- phase E: coop gate write (rows 32..95 -> own 64 rows) ----
    {
      ushort_t* gslot = gates + (size_t)j * G_ELEMS;
      int e = tid;                  // 512 groups total
      {
        int r = e >> 3, c0 = (e & 7) * 8;
        *(bf16x8*)(gslot + (row0 + t0 + r) * 64 + c0) =
            *(const bf16x8*)&gt[32 + r][c0];
      }
      e = tid + 384;
      if (e < 512) {
        int r = e >> 3, c0 = (e & 7) * 8;
        *(bf16x8*)(gslot + (row0 + t0 + r) * 64 + c0) =
            *(const bf16x8*)&gt[32 + r][c0];
      }
    }
  }
  __syncthreads();

  // ---- write back x rows 32..95 ----
  {
    int e = tid;
    {
      int r = e >> 3, c0 = (e & 7) * 8;
      *(bf16x8*)(xout + (row0 + t0 + r) * 64 + c0) = *(const bf16x8*)&xt[32 + r][c0];
    }
    e = tid + 384;
    if (e < 512) {
      int r = e >> 3, c0 = (e & 7) * 8;
      *(bf16x8*)(xout + (row0 + t0 + r) * 64 + c0) = *(const bf16x8*)&xt[32 + r][c0];
    }
  }
}

// ---------------------------------------------------------------------------
// Single layer (d >= 32): R13-exact. 512 blocks x 256 threads.
// ---------------------------------------------------------------------------
__global__ __launch_bounds__(256, 4) void layer_kernel(
    const ushort_t* __restrict__ xin, ushort_t* __restrict__ xout,
    ushort_t* __restrict__ gate_out,
    const ushort_t* __restrict__ wcat_s, const float* __restrict__ cb,
    const ushort_t* __restrict__ rww,    const float* __restrict__ rb,
    int d, int write_res)
{
  __shared__ __align__(16) ushort_t lwc[16384];    // 32 KB conv weights
  __shared__ __align__(16) ushort_t gt[64][72];    // 9 KB gate tile

  const int tid = threadIdx.x;
  const int w = tid >> 6, lane = tid & 63;
  const int quad = lane >> 4, c16 = lane & 15;
  const int bb = blockIdx.x >> 7;
  const int t0 = (blockIdx.x & 127) << 6;
  const int tb = t0 + w * 16;
  const size_t row0 = (size_t)bb * NT;

  {
    bf16x8* dst = (bf16x8*)lwc;
    const bf16x8* s1 = (const bf16x8*)wcat_s;
#pragma unroll
    for (int i = 0; i < 8; ++i) dst[tid + i * 256] = s1[tid + i * 256];
  }

  const int tA = tb + c16;
  bf16x8 af[4];
#pragma unroll
  for (int kk = 0; kk < 4; ++kk) {
    int ts = (kk < 2) ? (tA - d) : tA;
    int ch = (kk & 1) * 32 + quad * 8;
    if (ts >= 0) {
      af[kk] = *(const bf16x8*)(xin + (row0 + ts) * 64 + ch);
    } else {
      bf16x8 z = {0, 0, 0, 0, 0, 0, 0, 0};
      af[kk] = z;
    }
  }
  __syncthreads();

#pragma unroll
  for (int q = 0; q < 4; ++q) {
    int na = q * 16 + c16;
    int nb2 = na + 64;
    float ba = cb[na], bs = cb[nb2];
    f32x4 va = {ba, ba, ba, ba}, vb = {bs, bs, bs, bs};
#pragma unroll
    for (int kk = 0; kk < 4; ++kk) {
      va = MFMA(af[kk], *(const bf16x8*)&lwc[kk * 4096 + na * 32 + quad * 8], va);
      vb = MFMA(af[kk], *(const bf16x8*)&lwc[kk * 4096 + nb2 * 32 + quad * 8], vb);
    }
#pragma unroll
    for (int r = 0; r < 4; ++r) {
      float e2 = __expf(2.f * va[r]);
      float th = (e2 - 1.f) / (e2 + 1.f);
      float sg = 1.f / (1.f + __expf(-vb[r]));
      gt[w * 16 + quad * 4 + r][q * 16 + c16] = f2bu(th * sg);
    }
  }

  bf16x8 gf0 = *(const bf16x8*)&gt[w * 16 + c16][quad * 8];
  bf16x8 gf1 = *(const bf16x8*)&gt[w * 16 + c16][32 + quad * 8];

  if (write_res) {
    const ushort_t* wp2 = rww + c16 * 32 + quad * 8;
#pragma unroll
    for (int q = 0; q < 4; ++q) {
      int n = q * 16 + c16;
      float bv = rb[n];
      f32x4 acc = {bv, bv, bv, bv};
      acc = MFMA(gf0, *(const bf16x8*)(wp2 + q * 512), acc);
      acc = MFMA(gf1, *(const bf16x8*)(wp2 + q * 512 + 2048), acc);
#pragma unroll
      for (int r = 0; r < 4; ++r) {
        size_t idx = (row0 + tb + quad * 4 + r) * 64 + n;
        xout[idx] = f2bu(b2f(xin[idx]) + acc[r]);
      }
    }
  }

  // wave-local gate write (no barrier): own 16 rows, fully coalesced
#pragma unroll
  for (int i = 0; i < 2; ++i) {
    int e = lane + i * 64;
    int rr = w * 16 + (e >> 3), c0 = (e & 7) * 8;
    *(bf16x8*)(gate_out + (row0 + t0 + rr) * 64 + c0) = *(const bf16x8*)&gt[rr][c0];
  }
}

// ---------------------------------------------------------------------------
// Skip-group GEMM with LDS-staged weight chunks (groups 0..4).
// ---------------------------------------------------------------------------
__global__ __launch_bounds__(256) void skip_kernel(
    ushort_t* __restrict__ skip, const ushort_t* __restrict__ gates,
    const ushort_t* __restrict__ swg, const float* __restrict__ sbg,
    int first)
{
  __shared__ __align__(16) ushort_t wbuf[8192];   // 16 KB chunk
  const int tid = threadIdx.x;
  const int w = tid >> 6, lane = tid & 63;
  const int quad = lane >> 4, c16 = lane & 15;
  const int bb = blockIdx.x >> 7;
  const int t0 = (blockIdx.x & 127) << 6;
  const int tb = t0 + w * 16;
  const size_t row0 = (size_t)bb * NT;

  f32x4 acc[16];
#pragma unroll
  for (int nt = 0; nt < 16; ++nt) { f32x4 z = {0.f, 0.f, 0.f, 0.f}; acc[nt] = z; }

  const size_t arow = (row0 + tb + c16) * 64;
  for (int kk = 0; kk < 10; ++kk) {
#pragma unroll
    for (int i = 0; i < 4; ++i)
      ((bf16x8*)wbuf)[tid + i * 256] = ((const bf16x8*)(swg + kk * 8192))[tid + i * 256];
    __syncthreads();

    int slot = kk >> 1;
    bf16x8 af = *(const bf16x8*)(gates + (size_t)slot * G_ELEMS + arow +
                                 (kk & 1) * 32 + quad * 8);
    const ushort_t* wp = wbuf + c16 * 32 + quad * 8;
#pragma unroll
    for (int nt = 0; nt < 16; ++nt)
      acc[nt] = MFMA(af, *(const bf16x8*)(wp + nt * 512), acc[nt]);
    __syncthreads();
  }

#pragma unroll
  for (int nt = 0; nt < 16; ++nt) {
    int n = nt * 16 + c16;
    float sbn = sbg[n];
#pragma unroll
    for (int r = 0; r < 4; ++r) {
      size_t idx = (row0 + tb + quad * 4 + r) * 256 + n;
      float old = first ? 0.f : b2f(skip[idx]);
      skip[idx] = f2bu(old + acc[nt][r] + sbn);
    }
  }
}

// ---------------------------------------------------------------------------
// FUSED final skip GEMM (group 5) + head. The group-5 skip contribution is
// computed into registers, combined with the prior accumulation from global
// skip, and written straight into the head's LDS tile (no global skip write,
// no separate head dispatch / skip re-read). Tile rows are wave-private at
// every step, so only the wbuf staging barriers are needed.
// 512 blocks x 256 threads; block 64 rows; wave 16 rows x all 256 n.
// ---------------------------------------------------------------------------
__global__ __launch_bounds__(256) void skip_head_kernel(
    const ushort_t* __restrict__ skip, const ushort_t* __restrict__ gates,
    const ushort_t* __restrict__ swg, const float* __restrict__ sbg,
    const ushort_t* __restrict__ w0T, const float* __restrict__ b0,
    const ushort_t* __restrict__ w1T, const float* __restrict__ b1,
    const int* __restrict__ wf, const int* __restrict__ lens,
    float* __restrict__ loss)
{
  __shared__ __align__(16) ushort_t wbuf[8192];       // 16 KB chunk
  __shared__ __align__(16) ushort_t tile[64][264];    // 33.8 KB
  const int tid = threadIdx.x;
  const int w = tid >> 6, lane = tid & 63;
  const int quad = lane >> 4, c16 = lane & 15;
  const int bb = blockIdx.x >> 7;
  const int t0 = (blockIdx.x & 127) << 6;
  const int tb = t0 + w * 16;
  const size_t row0 = (size_t)bb * NT;
  const int mylen = lens[bb];

  // ---- phase 1: group-5 skip GEMM (K=320) into registers ----
  f32x4 acc[16];
#pragma unroll
  for (int nt = 0; nt < 16; ++nt) { f32x4 z = {0.f, 0.f, 0.f, 0.f}; acc[nt] = z; }

  const size_t arow = (row0 + tb + c16) * 64;
  for (int kk = 0; kk < 10; ++kk) {
#pragma unroll
    for (int i = 0; i < 4; ++i)
      ((bf16x8*)wbuf)[tid + i * 256] = ((const bf16x8*)(swg + kk * 8192))[tid + i * 256];
    __syncthreads();

    int slot = kk >> 1;
    bf16x8 af = *(const bf16x8*)(gates + (size_t)slot * G_ELEMS + arow +
                                 (kk & 1) * 32 + quad * 8);
    const ushort_t* wp = wbuf + c16 * 32 + quad * 8;
#pragma unroll
    for (int nt = 0; nt < 16; ++nt)
      acc[nt] = MFMA(af, *(const bf16x8*)(wp + nt * 512), acc[nt]);
    __syncthreads();
  }

  // ---- phase 2: final skip = prior accumulation + group-5 + bias -> tile ----
#pragma unroll
  for (int nt = 0; nt < 16; ++nt) {
    int n = nt * 16 + c16;
    float sbn = sbg[n];
#pragma unroll
    for (int r = 0; r < 4; ++r) {
      size_t idx = (row0 + tb + quad * 4 + r) * 256 + n;
      tile[w * 16 + quad * 4 + r][n] = f2bu(b2f(skip[idx]) + acc[nt][r] + sbn);
    }
  }
  // tile rows are wave-private; no barrier needed before same-wave reads.

  // ---- phase 3: hid = relu(skip @ w0 + b0) -> tile in place ----
  f32x4 accA[16];
#pragma unroll
  for (int nt = 0; nt < 16; ++nt) {
    float bv = b0[nt * 16 + c16];
    f32x4 z = {bv, bv, bv, bv};
    accA[nt] = z;
  }
  for (int kk = 0; kk < 8; ++kk) {
#pragma unroll
    for (int i = 0; i < 4; ++i)
      ((bf16x8*)wbuf)[tid + i * 256] = ((const bf16x8*)(w0T + kk * 8192))[tid + i * 256];
    __syncthreads();
    bf16x8 af = *(const bf16x8*)&tile[w * 16 + c16][kk * 32 + quad * 8];
    const ushort_t* wp = wbuf + c16 * 32 + quad * 8;
#pragma unroll
    for (int nt = 0; nt < 16; ++nt)
      accA[nt] = MFMA(af, *(const bf16x8*)(wp + nt * 512), accA[nt]);
    __syncthreads();
  }
#pragma unroll
  for (int nt = 0; nt < 16; ++nt)
#pragma unroll
    for (int r = 0; r < 4; ++r)
      tile[w * 16 + quad * 4 + r][nt * 16 + c16] = f2bu(fmaxf(accA[nt][r], 0.f));

  // ---- phase 4: logits = hid @ w1 + b1 ----
  f32x4 acc2[16];
#pragma unroll
  for (int nt = 0; nt < 16; ++nt) {
    float bv = b1[nt * 16 + c16];
    f32x4 z = {bv, bv, bv, bv};
    acc2[nt] = z;
  }
  for (int kk = 0; kk < 8; ++kk) {
#pragma unroll
    for (int i = 0; i < 4; ++i)
      ((bf16x8*)wbuf)[tid + i * 256] = ((const bf16x8*)(w1T + kk * 8192))[tid + i * 256];
    __syncthreads();
    bf16x8 hf = *(const bf16x8*)&tile[w * 16 + c16][kk * 32 + quad * 8];
    const ushort_t* wp = wbuf + c16 * 32 + quad * 8;
#pragma unroll
    for (int nt = 0; nt < 16; ++nt)
      acc2[nt] = MFMA(hf, *(const bf16x8*)(wp + nt * 512), acc2[nt]);
    __syncthreads();
  }

  int lblv[4];
#pragma unroll
  for (int r = 0; r < 4; ++r)
    lblv[r] = wf[row0 + tb + quad * 4 + r];

  // ---- phase 5: two-pass log-softmax + masked CE ----
  float local = 0.f;
#pragma unroll
  for (int r = 0; r < 4; ++r) {
    float m = -1e30f, tv = -1e30f;
#pragma unroll
    for (int nt = 0; nt < 16; ++nt) {
      float v = acc2[nt][r];
      m = fmaxf(m, v);
      if (lblv[r] == nt * 16 + c16) tv = v;
    }
#pragma unroll
    for (int dd = 1; dd < 16; dd <<= 1) m = fmaxf(m, __shfl_xor(m, dd));
    float s = 0.f;
#pragma unroll
    for (int nt = 0; nt < 16; ++nt) s += __expf(acc2[nt][r] - m);
#pragma unroll
    for (int dd = 1; dd < 16; dd <<= 1) {
      s += __shfl_xor(s, dd);
      tv = fmaxf(tv, __shfl_xor(tv, dd));
    }
    int t = tb + quad * 4 + r;
    if (c16 == 0 && t < mylen) local += (m + __logf(s)) - tv;
  }
#pragma unroll
  for (int dd = 1; dd < 64; dd <<= 1) local += __shfl_xor(local, dd);
  if (lane == 0 && local != 0.f) atomicAdd(loss, local);
}

__global__ void finalize_kernel(const int* __restrict__ lens,
                                float* __restrict__ out)
{
  if (threadIdx.x == 0) {
    float den = 0.f;
    for (int b = 0; b < NB; ++b) {
      int l = lens[b];
      if (l > NT) l = NT;
      den += (float)l;
    }
    out[0] = out[0] / fmaxf(den, 1.f);
  }
}

// ---------------------------------------------------------------------------
extern "C" void kernel_launch(void* const* d_in, const int* in_sizes, int n_in,
                              void* d_out, int out_size, void* d_ws, size_t ws_size,
                              hipStream_t stream) {
  const int*   wf     = (const int*)d_in[0];
  const int*   lens   = (const int*)d_in[1];
  const float* embed  = (const float*)d_in[2];
  const float* conv_w = (const float*)d_in[3];
  const float* conv_b = (const float*)d_in[4];
  const float* res_w  = (const float*)d_in[5];
  const float* res_b  = (const float*)d_in[6];
  const float* skip_w = (const float*)d_in[7];
  const float* skip_b = (const float*)d_in[8];
  const float* w0     = (const float*)d_in[9];
  const float* b0     = (const float*)d_in[10];
  const float* w1     = (const float*)d_in[11];
  const float* b1     = (const float*)d_in[12];

  float* out = (float*)d_out;
  if (ws_size < WS_NEEDED) {
    sentinel_kernel<<<1, 64, 0, stream>>>(out);
    return;
  }

  ushort_t* x0    = (ushort_t*)d_ws;            // 4 MB
  ushort_t* x1    = x0 + X_ELEMS;               // 4 MB
  ushort_t* skip  = x1 + X_ELEMS;               // 16 MB
  ushort_t* gates = skip + SK_ELEMS;            // 5 x 4 MB
  ushort_t* wt    = gates + 5 * (size_t)G_ELEMS;// 2.42 MB
  float*    sbg   = (float*)(wt + TOTAL_W);     // 6 KB

  prep_kernel<<<(N_PREP + 255) / 256, 256, 0, stream>>>(
      conv_w, res_w, skip_w, w0, w1, skip_b, wt, sbg);
  embed_kernel<<<512, 256, 0, stream>>>(wf, embed, x0);
  zero_kernel<<<1, 64, 0, stream>>>(out);

  const ushort_t* xin = x0;
  ushort_t* xout = x1;
  static const int dil[NL] = {1, 2, 4, 8, 16, 32, 64, 128, 256, 512,
                              1, 2, 4, 8, 16, 32, 64, 128, 256, 512,
                              1, 2, 4, 8, 16, 32, 64, 128, 256, 512};
  for (int blk = 0; blk < 3; ++blk) {
    const int l0 = blk * 10;
    chain5_kernel<<<512, 384, 0, stream>>>(
        xin, xout, gates, wt, conv_b, res_b, l0);
    { const ushort_t* t = xout; xout = (ushort_t*)xin; xin = t; }
    skip_kernel<<<512, 256, 0, stream>>>(
        skip, gates, wt + OFF_SWG + (2 * blk) * 81920,
        sbg + (2 * blk) * 256, blk == 0 ? 1 : 0);
    for (int l = l0 + 5; l < l0 + 10; ++l) {
      layer_kernel<<<512, 256, 0, stream>>>(
          xin, xout, gates + (size_t)(l % 5) * G_ELEMS,
          wt + OFF_WCAT + l * 16384, conv_b + l * 128,
          wt + OFF_RW + l * 4096,    res_b + l * 64,
          dil[l], l < NL - 1 ? 1 : 0);
      { const ushort_t* t = xout; xout = (ushort_t*)xin; xin = t; }
    }
    if (blk < 2) {
      skip_kernel<<<512, 256, 0, stream>>>(
          skip, gates, wt + OFF_SWG + (2 * blk + 1) * 81920,
          sbg + (2 * blk + 1) * 256, 0);
    }
  }

  // fused: final skip GEMM (group 5) + head
  skip_head_kernel<<<512, 256, 0, stream>>>(
      skip, gates, wt + OFF_SWG + 5 * 81920, sbg + 5 * 256,
      wt + OFF_W0, b0, wt + OFF_W1, b1, wf, lens, out);
  finalize_kernel<<<1, 64, 0, stream>>>(lens, out);
}